// Round 1
// baseline (175.317 us; speedup 1.0000x reference)
//
#include <hip/hip_runtime.h>

#define N_NODES 50000
#define IN_FEAT 512
#define OUT_FEAT 256
#define N_EDGES 1600000
#define ALPHA 0.2f

// Kernel 1: fold W into the attention vectors.
// w_src[i] = sum_j W[i][j] * attn_w[j];  w_tgt[i] = sum_j W[i][j] * attn_w[OUT_FEAT+j]
// One wave (64 lanes) per row i; lane l covers columns [4l, 4l+4) -> 64*4 = 256 = OUT_FEAT.
__global__ void fold_w_kernel(const float* __restrict__ W,
                              const float* __restrict__ attn_w,
                              float* __restrict__ w_src,
                              float* __restrict__ w_tgt) {
    int row  = (blockIdx.x * blockDim.x + threadIdx.x) >> 6;
    int lane = threadIdx.x & 63;
    if (row >= IN_FEAT) return;
    const float4 wv = *(const float4*)(W + (size_t)row * OUT_FEAT + lane * 4);
    const float4 as = *(const float4*)(attn_w + lane * 4);
    const float4 at = *(const float4*)(attn_w + OUT_FEAT + lane * 4);
    float ssum = wv.x * as.x + wv.y * as.y + wv.z * as.z + wv.w * as.w;
    float tsum = wv.x * at.x + wv.y * at.y + wv.z * at.z + wv.w * at.w;
    #pragma unroll
    for (int off = 32; off > 0; off >>= 1) {
        ssum += __shfl_down(ssum, off, 64);
        tsum += __shfl_down(tsum, off, 64);
    }
    if (lane == 0) {
        w_src[row] = ssum;
        w_tgt[row] = tsum;
    }
}

// Kernel 2: per-node scores. s_src[n] = h[n,:] . w_src ; s_tgt[n] = h[n,:] . w_tgt
// One wave per node; lane l reads 8 contiguous floats (2x float4) of the 512-float row.
// 64 lanes * 8 = 512 = IN_FEAT, one fully coalesced 2KB row read per wave.
__global__ void node_scores_kernel(const float* __restrict__ h,
                                   const float* __restrict__ w_src,
                                   const float* __restrict__ w_tgt,
                                   float* __restrict__ s_src,
                                   float* __restrict__ s_tgt) {
    int node = (blockIdx.x * blockDim.x + threadIdx.x) >> 6;
    int lane = threadIdx.x & 63;
    if (node >= N_NODES) return;
    const float* hrow = h + (size_t)node * IN_FEAT + lane * 8;
    const float4 h0 = *(const float4*)(hrow);
    const float4 h1 = *(const float4*)(hrow + 4);
    const float4 ws0 = *(const float4*)(w_src + lane * 8);
    const float4 ws1 = *(const float4*)(w_src + lane * 8 + 4);
    const float4 wt0 = *(const float4*)(w_tgt + lane * 8);
    const float4 wt1 = *(const float4*)(w_tgt + lane * 8 + 4);
    float ssum = h0.x * ws0.x + h0.y * ws0.y + h0.z * ws0.z + h0.w * ws0.w
               + h1.x * ws1.x + h1.y * ws1.y + h1.z * ws1.z + h1.w * ws1.w;
    float tsum = h0.x * wt0.x + h0.y * wt0.y + h0.z * wt0.z + h0.w * wt0.w
               + h1.x * wt1.x + h1.y * wt1.y + h1.z * wt1.z + h1.w * wt1.w;
    #pragma unroll
    for (int off = 32; off > 0; off >>= 1) {
        ssum += __shfl_down(ssum, off, 64);
        tsum += __shfl_down(tsum, off, 64);
    }
    if (lane == 0) {
        s_src[node] = ssum;
        s_tgt[node] = tsum;
    }
}

// Kernel 3: per-edge gather + leaky_relu. 4 edges per thread via int4/float4.
// Score arrays are 200KB each -> L2-resident; edge-list reads and output writes coalesced.
__global__ void edge_kernel(const int* __restrict__ el,
                            const float* __restrict__ s_src,
                            const float* __restrict__ s_tgt,
                            float* __restrict__ out) {
    int i = blockIdx.x * blockDim.x + threadIdx.x;
    int base = i * 4;
    if (base >= N_EDGES) return;
    const int4 src = *(const int4*)(el + base);
    const int4 tgt = *(const int4*)(el + N_EDGES + base);
    float4 r;
    float v;
    v = s_src[src.x] + s_tgt[tgt.x]; r.x = v > 0.0f ? v : ALPHA * v;
    v = s_src[src.y] + s_tgt[tgt.y]; r.y = v > 0.0f ? v : ALPHA * v;
    v = s_src[src.z] + s_tgt[tgt.z]; r.z = v > 0.0f ? v : ALPHA * v;
    v = s_src[src.w] + s_tgt[tgt.w]; r.w = v > 0.0f ? v : ALPHA * v;
    *(float4*)(out + base) = r;
}

extern "C" void kernel_launch(void* const* d_in, const int* in_sizes, int n_in,
                              void* d_out, int out_size, void* d_ws, size_t ws_size,
                              hipStream_t stream) {
    const float* h      = (const float*)d_in[0];
    const int*   el     = (const int*)d_in[1];   // harness delivers integer inputs as int32
    const float* W      = (const float*)d_in[2];
    const float* attn_w = (const float*)d_in[3];
    float* out = (float*)d_out;

    // Workspace layout (floats): [0,512) w_src | [512,1024) w_tgt | [1024,51024) s_src | [51024,101024) s_tgt
    float* ws_f   = (float*)d_ws;
    float* w_src  = ws_f;
    float* w_tgt  = ws_f + IN_FEAT;
    float* s_src  = ws_f + 2 * IN_FEAT;
    float* s_tgt  = ws_f + 2 * IN_FEAT + N_NODES;

    // Kernel 1: 512 rows, one wave each -> 512*64 threads = 128 blocks of 256
    fold_w_kernel<<<(IN_FEAT * 64) / 256, 256, 0, stream>>>(W, attn_w, w_src, w_tgt);

    // Kernel 2: 50000 nodes, one wave each -> 50000*64/256 = 12500 blocks
    node_scores_kernel<<<(N_NODES * 64 + 255) / 256, 256, 0, stream>>>(h, w_src, w_tgt, s_src, s_tgt);

    // Kernel 3: 1.6M edges, 4 per thread -> 400000 threads
    edge_kernel<<<(N_EDGES / 4 + 255) / 256, 256, 0, stream>>>(el, s_src, s_tgt, out);
}

// Round 2
// 173.284 us; speedup vs baseline: 1.0117x; 1.0117x over previous
//
#include <hip/hip_runtime.h>

#define N_NODES 50000
#define IN_FEAT 512
#define OUT_FEAT 256
#define N_EDGES 1600000
#define ALPHA 0.2f

typedef float v4f __attribute__((ext_vector_type(4)));
typedef int   v4i __attribute__((ext_vector_type(4)));

// Kernel 1: fold W into the attention vectors (tiny: 512x256x2 MACs).
// w_src[i] = sum_j W[i][j]*attn_w[j];  w_tgt[i] = sum_j W[i][j]*attn_w[OUT_FEAT+j]
// One wave per row; lane l covers columns [4l,4l+4).
__global__ void fold_w_kernel(const float* __restrict__ W,
                              const float* __restrict__ attn_w,
                              float* __restrict__ w_src,
                              float* __restrict__ w_tgt) {
    int row  = (blockIdx.x * blockDim.x + threadIdx.x) >> 6;
    int lane = threadIdx.x & 63;
    if (row >= IN_FEAT) return;
    const v4f wv = *(const v4f*)(W + (size_t)row * OUT_FEAT + lane * 4);
    const v4f as = *(const v4f*)(attn_w + lane * 4);
    const v4f at = *(const v4f*)(attn_w + OUT_FEAT + lane * 4);
    float ssum = wv.x * as.x + wv.y * as.y + wv.z * as.z + wv.w * as.w;
    float tsum = wv.x * at.x + wv.y * at.y + wv.z * at.z + wv.w * at.w;
    #pragma unroll
    for (int off = 32; off > 0; off >>= 1) {
        ssum += __shfl_down(ssum, off, 64);
        tsum += __shfl_down(tsum, off, 64);
    }
    if (lane == 0) {
        w_src[row] = ssum;
        w_tgt[row] = tsum;
    }
}

// Kernel 2: per-node scores. s_src[n] = h[n,:].w_src ; s_tgt[n] = h[n,:].w_tgt
// One wave per node; lane l reads 8 contiguous floats (2x float4, non-temporal —
// h is 102 MB streamed once, keep it out of L2). w vectors stay cached (hot).
__global__ void node_scores_kernel(const float* __restrict__ h,
                                   const float* __restrict__ w_src,
                                   const float* __restrict__ w_tgt,
                                   float* __restrict__ s_src,
                                   float* __restrict__ s_tgt) {
    int node = (blockIdx.x * blockDim.x + threadIdx.x) >> 6;
    int lane = threadIdx.x & 63;
    if (node >= N_NODES) return;
    const v4f* hrow = (const v4f*)(h + (size_t)node * IN_FEAT + lane * 8);
    const v4f h0 = __builtin_nontemporal_load(hrow);
    const v4f h1 = __builtin_nontemporal_load(hrow + 1);
    const v4f ws0 = *(const v4f*)(w_src + lane * 8);
    const v4f ws1 = *(const v4f*)(w_src + lane * 8 + 4);
    const v4f wt0 = *(const v4f*)(w_tgt + lane * 8);
    const v4f wt1 = *(const v4f*)(w_tgt + lane * 8 + 4);
    float ssum = h0.x * ws0.x + h0.y * ws0.y + h0.z * ws0.z + h0.w * ws0.w
               + h1.x * ws1.x + h1.y * ws1.y + h1.z * ws1.z + h1.w * ws1.w;
    float tsum = h0.x * wt0.x + h0.y * wt0.y + h0.z * wt0.z + h0.w * wt0.w
               + h1.x * wt1.x + h1.y * wt1.y + h1.z * wt1.z + h1.w * wt1.w;
    #pragma unroll
    for (int off = 32; off > 0; off >>= 1) {
        ssum += __shfl_down(ssum, off, 64);
        tsum += __shfl_down(tsum, off, 64);
    }
    if (lane == 0) {
        s_src[node] = ssum;
        s_tgt[node] = tsum;
    }
}

// Kernel 3: per-edge gather + leaky_relu. 8 edges per thread.
// Edge list / out are streaming (non-temporal); score arrays (2x200KB) stay in L2
// for the random gathers.
__global__ void edge_kernel(const int* __restrict__ el,
                            const float* __restrict__ s_src,
                            const float* __restrict__ s_tgt,
                            float* __restrict__ out) {
    int i = blockIdx.x * blockDim.x + threadIdx.x;
    int base = i * 8;
    if (base >= N_EDGES) return;
    const v4i* sp = (const v4i*)(el + base);
    const v4i* tp = (const v4i*)(el + N_EDGES + base);
    v4i src0 = __builtin_nontemporal_load(sp);
    v4i src1 = __builtin_nontemporal_load(sp + 1);
    v4i tgt0 = __builtin_nontemporal_load(tp);
    v4i tgt1 = __builtin_nontemporal_load(tp + 1);
    v4f r0, r1;
    float v;
    v = s_src[src0.x] + s_tgt[tgt0.x]; r0.x = v > 0.0f ? v : ALPHA * v;
    v = s_src[src0.y] + s_tgt[tgt0.y]; r0.y = v > 0.0f ? v : ALPHA * v;
    v = s_src[src0.z] + s_tgt[tgt0.z]; r0.z = v > 0.0f ? v : ALPHA * v;
    v = s_src[src0.w] + s_tgt[tgt0.w]; r0.w = v > 0.0f ? v : ALPHA * v;
    v = s_src[src1.x] + s_tgt[tgt1.x]; r1.x = v > 0.0f ? v : ALPHA * v;
    v = s_src[src1.y] + s_tgt[tgt1.y]; r1.y = v > 0.0f ? v : ALPHA * v;
    v = s_src[src1.z] + s_tgt[tgt1.z]; r1.z = v > 0.0f ? v : ALPHA * v;
    v = s_src[src1.w] + s_tgt[tgt1.w]; r1.w = v > 0.0f ? v : ALPHA * v;
    v4f* op = (v4f*)(out + base);
    __builtin_nontemporal_store(r0, op);
    __builtin_nontemporal_store(r1, op + 1);
}

extern "C" void kernel_launch(void* const* d_in, const int* in_sizes, int n_in,
                              void* d_out, int out_size, void* d_ws, size_t ws_size,
                              hipStream_t stream) {
    const float* h      = (const float*)d_in[0];
    const int*   el     = (const int*)d_in[1];   // int inputs arrive as int32
    const float* W      = (const float*)d_in[2];
    const float* attn_w = (const float*)d_in[3];
    float* out = (float*)d_out;

    // Workspace (floats): [0,512) w_src | [512,1024) w_tgt | [1024,51024) s_src | [51024,101024) s_tgt
    float* ws_f   = (float*)d_ws;
    float* w_src  = ws_f;
    float* w_tgt  = ws_f + IN_FEAT;
    float* s_src  = ws_f + 2 * IN_FEAT;
    float* s_tgt  = ws_f + 2 * IN_FEAT + N_NODES;

    // Kernel 1: 512 rows, one wave each -> 128 blocks of 256
    fold_w_kernel<<<(IN_FEAT * 64) / 256, 256, 0, stream>>>(W, attn_w, w_src, w_tgt);

    // Kernel 2: 50000 nodes, one wave each -> 12500 blocks
    node_scores_kernel<<<(N_NODES * 64 + 255) / 256, 256, 0, stream>>>(h, w_src, w_tgt, s_src, s_tgt);

    // Kernel 3: 1.6M edges, 8 per thread -> 200000 threads -> 782 blocks
    edge_kernel<<<(N_EDGES / 8 + 255) / 256, 256, 0, stream>>>(el, s_src, s_tgt, out);
}